// Round 9
// baseline (264.654 us; speedup 1.0000x reference)
//
#include <hip/hip_runtime.h>

// Problem constants
#define P_TOTAL 132096
#define NPOOL   4096
#define GDIM    1000
#define HDIM    150
#define MGRP    2048
#define KMAX    128

typedef __attribute__((ext_vector_type(4))) float f32x4;
typedef __attribute__((ext_vector_type(2))) float f32x2;
typedef __attribute__((ext_vector_type(4))) unsigned int u32x4;

// ---------- workspace layout (bytes) ----------
#define OFF_W1C8   0
#define OFF_W1AB8  163840
#define OFF_W2F8   491520
#define OFF_ABPRE  517120
#define OFF_TABS2  3138560
#define OFF_SGRID  3276800
#define OFF_GF8    4325376
#define OFF_ITAB   8519680

__device__ __forceinline__ short f2bf(float f) {
  union { float f; unsigned u; } v; v.f = f;
  unsigned r = v.u + 0x7FFFu + ((v.u >> 16) & 1u);   // RNE
  return (short)(r >> 16);
}
__device__ __forceinline__ float bf2f(unsigned short s) {
  return __builtin_bit_cast(float, ((unsigned)s) << 16);
}
__device__ __forceinline__ unsigned char f2fp8(float f) {
  int d = __builtin_amdgcn_cvt_pk_fp8_f32(f, 0.f, 0, false);
  return (unsigned char)(d & 0xFF);
}
__device__ __forceinline__ long mk64(unsigned lo, unsigned hi) {
  return (long)(((unsigned long long)hi << 32) | lo);
}

// 16 fp8 x 16 fp8 -> elementwise product, requantized fp8
__device__ __forceinline__ u32x4 fp8prod16(u32x4 m, u32x4 a) {
  u32x4 r;
  #pragma unroll
  for (int d = 0; d < 4; ++d) {
    f32x2 ml = __builtin_amdgcn_cvt_pk_f32_fp8(m[d], false);
    f32x2 mh = __builtin_amdgcn_cvt_pk_f32_fp8(m[d], true);
    f32x2 al = __builtin_amdgcn_cvt_pk_f32_fp8(a[d], false);
    f32x2 ah = __builtin_amdgcn_cvt_pk_f32_fp8(a[d], true);
    f32x2 pl = ml * al, ph = mh * ah;
    int o = __builtin_amdgcn_cvt_pk_fp8_f32(pl[0], pl[1], 0, false);
    o = __builtin_amdgcn_cvt_pk_fp8_f32(ph[0], ph[1], o, true);
    r[d] = (unsigned)o;
  }
  return r;
}

// pack two f32 -> one u32 of 2 bf16 (RNE), single instruction on gfx950
__device__ __forceinline__ unsigned pk_bf16(float lo, float hi) {
  unsigned o;
  asm("v_cvt_pk_bf16_f32 %0, %1, %2" : "=v"(o) : "v"(lo), "v"(hi));
  return o;
}

// ---------- kernel 1: merged prep ----------
#define S1 5120
#define S2 10240
#define S3 800
#define S4 (NPOOL*256)
#define S5 (216*160)
#define S6 P_TOTAL
__global__ __launch_bounds__(256) void prep_kernel(
    const float* __restrict__ W1, const float* __restrict__ W2,
    const float* __restrict__ g_i,
    const float* __restrict__ dist_emb, const float* __restrict__ genre_emb,
    const float* __restrict__ spk_emb, const float* __restrict__ b1,
    const int* __restrict__ did, const int* __restrict__ gid,
    const int* __restrict__ sid,
    unsigned char* __restrict__ w1c8, unsigned char* __restrict__ w1ab8,
    unsigned char* __restrict__ w2f8, unsigned* __restrict__ gf8,
    float* __restrict__ tabs2, unsigned char* __restrict__ itab8) {
  int idx = blockIdx.x * 256 + threadIdx.x;
  if (idx < S1) {                               // w1c8 [c][n][kk], coalesced-in-n reads
    int c = idx / 160, n = idx % 160;
    int s = c >> 1, j = c & 1;
    unsigned dw[8];
    #pragma unroll
    for (int d = 0; d < 8; ++d) {
      unsigned acc = 0;
      #pragma unroll
      for (int b = 0; b < 4; ++b) {
        int kk = d*4 + b;
        int g = kk >> 3, i = kk & 7;
        int q = g ^ ((n >> 2) & 3);             // bank swizzle baked
        int k = s*64 + q*16 + j*8 + i;
        float v = (k < GDIM && n < HDIM) ? W1[(2000 + k)*HDIM + n] : 0.f;
        acc |= ((unsigned)f2fp8(v)) << (8*b);
      }
      dw[d] = acc;
    }
    u32x4 lo = {dw[0], dw[1], dw[2], dw[3]};
    u32x4 hi = {dw[4], dw[5], dw[6], dw[7]};
    *(u32x4*)(w1c8 + c*5120 + n*32)      = lo;
    *(u32x4*)(w1c8 + c*5120 + n*32 + 16) = hi;
  } else if (idx < S1 + S2) {                   // w1ab8 [c][n][kk], BK=128 K-perm
    int i2 = idx - S1;
    int c = i2 / 320, n = i2 % 320;
    int s = c >> 2, j = c & 3;
    unsigned dw[8];
    #pragma unroll
    for (int d = 0; d < 8; ++d) {
      unsigned acc = 0;
      #pragma unroll
      for (int b = 0; b < 4; ++b) {
        int kk = d*4 + b;
        int g = kk >> 3, i = kk & 7;
        int k = s*128 + g*32 + j*8 + i;
        float v = 0.f;
        if (k < GDIM) {
          if (n < HDIM)                 v = W1[k*HDIM + n];
          else if (n >= 160 && n < 310) v = W1[(1000 + k)*HDIM + (n - 160)];
        }
        acc |= ((unsigned)f2fp8(v)) << (8*b);
      }
      dw[d] = acc;
    }
    u32x4 lo = {dw[0], dw[1], dw[2], dw[3]};
    u32x4 hi = {dw[4], dw[5], dw[6], dw[7]};
    *(u32x4*)(w1ab8 + c*10240 + n*32)      = lo;
    *(u32x4*)(w1ab8 + c*10240 + n*32 + 16) = hi;
  } else if (idx < S1 + S2 + S3) {              // w2f8 [c][n][kk], bank swizzle
    int i2 = idx - S1 - S2;
    int c = i2 / 160, n = i2 % 160;
    unsigned dw[8];
    #pragma unroll
    for (int d = 0; d < 8; ++d) {
      unsigned acc = 0;
      #pragma unroll
      for (int b = 0; b < 4; ++b) {
        int kk = d*4 + b;
        int g = kk >> 3, ii = kk & 7;
        int q = g ^ ((n >> 2) & 3);
        int k = c*32 + q*8 + ii;
        float v = (k < HDIM && n < HDIM) ? W2[k*HDIM + n] : 0.f;
        acc |= ((unsigned)f2fp8(v)) << (8*b);
      }
      dw[d] = acc;
    }
    u32x4 lo = {dw[0], dw[1], dw[2], dw[3]};
    u32x4 hi = {dw[4], dw[5], dw[6], dw[7]};
    *(u32x4*)(w2f8 + c*5120 + n*32)      = lo;
    *(u32x4*)(w2f8 + c*5120 + n*32 + 16) = hi;
  } else if (idx < S1 + S2 + S3 + S4) {         // g_i -> fp8 [4096][1024]
    int i = idx - S1 - S2 - S3;
    int row = i >> 8, jd = i & 255;
    int c0 = jd * 4;
    float f0 = (c0     < GDIM) ? g_i[row*GDIM + c0]     : 0.f;
    float f1 = (c0 + 1 < GDIM) ? g_i[row*GDIM + c0 + 1] : 0.f;
    float f2 = (c0 + 2 < GDIM) ? g_i[row*GDIM + c0 + 2] : 0.f;
    float f3 = (c0 + 3 < GDIM) ? g_i[row*GDIM + c0 + 3] : 0.f;
    int d = 0;
    d = __builtin_amdgcn_cvt_pk_fp8_f32(f0, f1, d, false);
    d = __builtin_amdgcn_cvt_pk_fp8_f32(f2, f3, d, true);
    gf8[i] = (unsigned)d;
  } else if (idx < S1 + S2 + S3 + S4 + S5) {    // tabs2: combo phi rows (b1 folded)
    int i = idx - S1 - S2 - S3 - S4;
    int row = i / 160, n = i % 160;
    float acc = 0.f;
    if (n < HDIM) {
      int d = row / 24, g = (row / 3) % 8, sp = row % 3;
      acc = b1[n];
      #pragma unroll
      for (int kk = 0; kk < 20; ++kk) {
        acc += dist_emb [d*20 + kk]  * W1[(3000 + kk)*HDIM + n];
        acc += genre_emb[g*20 + kk]  * W1[(3020 + kk)*HDIM + n];
        acc += spk_emb  [sp*20 + kk] * W1[(3040 + kk)*HDIM + n];
      }
    }
    tabs2[i] = acc;
  } else if (idx < S1 + S2 + S3 + S4 + S5 + S6) {  // itab8: packed combo index
    int p = idx - (S1 + S2 + S3 + S4 + S5);
    itab8[p] = (unsigned char)(did[p]*24 + gid[p]*3 + sid[p]);
  }
}

// ---------- kernel 2: abpre[4096][320](bf16) = g @ [W1a|W1b], fp8 MFMA ----------
__global__ __launch_bounds__(128) void pre_gemm_kernel(
    const unsigned char* __restrict__ gf8, const unsigned char* __restrict__ w1ab8,
    unsigned short* __restrict__ abpre) {
  int wave = threadIdx.x >> 6, lane = threadIdx.x & 63;
  int quad = lane >> 4, n16 = lane & 15;
  int rowbase = blockIdx.x * 32 + wave * 16;
  int colbase = blockIdx.y * 80;

  f32x4 acc[5];
  #pragma unroll
  for (int t = 0; t < 5; ++t) acc[t] = (f32x4){0.f, 0.f, 0.f, 0.f};

  const unsigned char* arow = gf8 + (long)(rowbase + n16) * 1024 + quad*32;

  for (int s = 0; s < 8; ++s) {
    u32x4 Aa = *(const u32x4*)(arow + s*128);
    u32x4 Ab = *(const u32x4*)(arow + s*128 + 16);
    #pragma unroll
    for (int j = 0; j < 4; ++j) {
      long a = (j == 0) ? mk64(Aa[0], Aa[1]) : (j == 1) ? mk64(Aa[2], Aa[3])
             : (j == 2) ? mk64(Ab[0], Ab[1]) : mk64(Ab[2], Ab[3]);
      const unsigned char* bp = w1ab8 + (((s*4 + j)*320 + colbase + n16) * 32 + quad*8);
      #pragma unroll
      for (int t = 0; t < 5; ++t) {
        long b = *(const long*)(bp + t*16*32);
        acc[t] = __builtin_amdgcn_mfma_f32_16x16x32_fp8_fp8(a, b, acc[t], 0, 0, 0);
      }
    }
  }
  #pragma unroll
  for (int t = 0; t < 5; ++t) {
    #pragma unroll
    for (int r = 0; r < 4; ++r) {
      int row = rowbase + quad*4 + r;
      abpre[(long)row * 320 + colbase + t*16 + n16] = (unsigned short)f2bf(acc[t][r]);
    }
  }
}

// ---------- kernel 3: MLP. A-operands direct global->VGPR (per-lane gather,
// identical 16x64B transactions as the old LDS-DMA path but no LDS round-trip:
// A staging had ZERO cross-wave sharing). LDS holds only the genuinely shared
// W1c double buffer (2 x 10240) + epilogue overlay. LDS 40960. ----------------
__global__ __launch_bounds__(256) void mlp_kernel(
    const unsigned char* __restrict__ gf8,
    const unsigned* __restrict__ abpre32,
    const float* __restrict__ tabs2,
    const unsigned char* __restrict__ itab8,
    const unsigned char* __restrict__ w1c8,
    const unsigned char* __restrict__ w2f8,
    const float* __restrict__ ms,
    const float* __restrict__ W3, const float* __restrict__ b2,
    const float* __restrict__ b3,
    const int* __restrict__ mention_ids, const int* __restrict__ antecedent_ids,
    const int* __restrict__ seg_ids, const int* __restrict__ offs,
    float* __restrict__ sgrid) {

  __shared__ __align__(16) unsigned char lds[40960];

  int tid = threadIdx.x;
  int wave = tid >> 6, lane = tid & 63;
  int quad = lane >> 4, n16 = lane & 15;
  int lp0 = blockIdx.x * 128;
  int gp0 = lp0;
  int wrow = wave * 32;
  int swB = quad ^ ((n16 >> 2) & 3);

  // per-lane A gather bases: lane (quad,n16) owns bytes [s*64+quad*16,+16)
  // of its pair rows (pairs wrow+n16 and wrow+16+n16)
  const unsigned char* pM0 =
      gf8 + (long)mention_ids[gp0 + wrow + n16] * 1024 + quad*16;
  const unsigned char* pM1 =
      gf8 + (long)mention_ids[gp0 + wrow + 16 + n16] * 1024 + quad*16;
  const unsigned char* pC0 =
      gf8 + (long)antecedent_ids[gp0 + wrow + n16] * 1024 + quad*16;
  const unsigned char* pC1 =
      gf8 + (long)antecedent_ids[gp0 + wrow + 16 + n16] * 1024 + quad*16;

  f32x4 acc0[10], acc1[10];
  #pragma unroll
  for (int t = 0; t < 10; ++t) {
    acc0[t] = (f32x4){0.f, 0.f, 0.f, 0.f};
    acc1[t] = (f32x4){0.f, 0.f, 0.f, 0.f};
  }

  auto issueW = [&](int s, int buf) {
    unsigned char* base = lds + buf*10240;
    const unsigned char* wsrc = w1c8 + (long)s*10240;
    __builtin_amdgcn_global_load_lds((const unsigned int*)(wsrc + wave*1024 + (long)lane*16),
        (unsigned int*)(base + wave*1024 + lane*16), 16, 0, 0);
    __builtin_amdgcn_global_load_lds((const unsigned int*)(wsrc + (wave+4)*1024 + (long)lane*16),
        (unsigned int*)(base + (wave+4)*1024 + lane*16), 16, 0, 0);
    if (wave < 2)
      __builtin_amdgcn_global_load_lds((const unsigned int*)(wsrc + (wave+8)*1024 + (long)lane*16),
          (unsigned int*)(base + (wave+8)*1024 + lane*16), 16, 0, 0);
  };

  u32x4 cM0 = *(const u32x4*)pM0;
  u32x4 cM1 = *(const u32x4*)pM1;
  u32x4 cC0 = *(const u32x4*)pC0;
  u32x4 cC1 = *(const u32x4*)pC1;
  issueW(0, 0);

  #pragma unroll 2
  for (int s = 0; s < 16; ++s) {
    __syncthreads();                       // W buf[s&1] landed
    if (s < 15) issueW(s + 1, (s + 1) & 1);
    u32x4 nM0, nM1, nC0, nC1;
    if (s < 15) {                          // prefetch next-step A into regs
      nM0 = *(const u32x4*)(pM0 + (s + 1)*64);
      nM1 = *(const u32x4*)(pM1 + (s + 1)*64);
      nC0 = *(const u32x4*)(pC0 + (s + 1)*64);
      nC1 = *(const u32x4*)(pC1 + (s + 1)*64);
    }
    const unsigned char* cb = lds + (s & 1)*10240;

    u32x4 P0 = fp8prod16(cM0, cC0);
    u32x4 P1 = fp8prod16(cM1, cC1);

    #pragma unroll
    for (int j = 0; j < 2; ++j) {
      long a0 = (j == 0) ? mk64(P0[0], P0[1]) : mk64(P0[2], P0[3]);
      long a1 = (j == 0) ? mk64(P1[0], P1[1]) : mk64(P1[2], P1[3]);
      const unsigned char* bp = cb + j*5120 + n16*32 + swB*8;
      #pragma unroll
      for (int t = 0; t < 10; ++t) {
        long b = *(const long*)(bp + t*512);
        acc0[t] = __builtin_amdgcn_mfma_f32_16x16x32_fp8_fp8(a0, b, acc0[t], 0, 0, 0);
        acc1[t] = __builtin_amdgcn_mfma_f32_16x16x32_fp8_fp8(a1, b, acc1[t], 0, 0, 0);
      }
    }
    if (s < 15) { cM0 = nM0; cM1 = nM1; cC0 = nC0; cC1 = nC1; }
  }
  __syncthreads();   // all waves done reading W buffers

  // ---- fused extras (all LDS below is wave-private -> no barriers needed)
  unsigned char* h1w = lds + wave * 5120;                  // [32][160] fp8, XOR-swz
  unsigned* extw = (unsigned*)(lds + 20480 + wave*5120);   // [16][80] u32
  const unsigned short* ext16 = (const unsigned short*)extw;
  int rowi = lane >> 2, q4 = lane & 3;

  #pragma unroll
  for (int p = 0; p < 2; ++p) {
    int gpe = gp0 + wrow + p*16 + rowi;
    int m  = mention_ids[gpe];
    int a  = antecedent_ids[gpe];
    int it = itab8[gpe];
    const u32x4* pm = (const u32x4*)(abpre32 + (long)m*160 + q4*20);
    const u32x4* pa = (const u32x4*)(abpre32 + (long)a*160 + 80 + q4*20);
    const f32x4* tb = (const f32x4*)(tabs2 + (long)it*160 + q4*40);
    #pragma unroll
    for (int k = 0; k < 5; ++k) {
      u32x4 um = pm[k], ua = pa[k];
      f32x4 ta = tb[2*k], tc = tb[2*k + 1];
      u32x4 ov;
      #pragma unroll
      for (int d = 0; d < 4; ++d) {
        float f0 = (d == 0) ? ta[0] : (d == 1) ? ta[2] : (d == 2) ? tc[0] : tc[2];
        float f1 = (d == 0) ? ta[1] : (d == 1) ? ta[3] : (d == 2) ? tc[1] : tc[3];
        float v0 = bf2f((unsigned short)(um[d] & 0xffff))
                 + bf2f((unsigned short)(ua[d] & 0xffff)) + f0;
        float v1 = bf2f((unsigned short)(um[d] >> 16))
                 + bf2f((unsigned short)(ua[d] >> 16)) + f1;
        ov[d] = pk_bf16(v0, v1);
      }
      *(u32x4*)(extw + rowi*80 + q4*20 + 4*k) = ov;
    }
    #pragma unroll
    for (int r = 0; r < 4; ++r) {
      int lr = quad*4 + r;
      int row = p*16 + lr;
      int xr = (lr & 12) << 1;
      #pragma unroll
      for (int t = 0; t < 10; ++t) {
        int n = t*16 + n16;
        float e = bf2f(ext16[lr*160 + n]);
        float v = ((p == 0) ? acc0[t][r] : acc1[t][r]) + e;
        h1w[row*160 + (n ^ xr)] = f2fp8(fmaxf(v, 0.f));
      }
    }
  }

  float bias3 = b3[0];
  float w3v[10], b2v[10];
  #pragma unroll
  for (int t = 0; t < 10; ++t) {
    int n = t*16 + n16;
    w3v[t] = (n < HDIM) ? W3[n] : 0.f;
    b2v[t] = (n < HDIM) ? b2[n] : 0.f;
  }

  #pragma unroll
  for (int tile = 0; tile < 2; ++tile) {
    f32x4 acc2[10];
    #pragma unroll
    for (int t = 0; t < 10; ++t) acc2[t] = (f32x4){0.f, 0.f, 0.f, 0.f};

    int row = tile*16 + n16;
    int xr = (row & 12) << 1;
    #pragma unroll
    for (int c = 0; c < 5; ++c) {
      long a = *(const long*)(h1w + row*160 + ((c*32 + quad*8) ^ xr));
      const unsigned char* bp = w2f8 + ((long)c*160 + n16)*32 + swB*8;
      #pragma unroll
      for (int t = 0; t < 10; ++t) {
        long b = *(const long*)(bp + t*512);
        acc2[t] = __builtin_amdgcn_mfma_f32_16x16x32_fp8_fp8(a, b, acc2[t], 0, 0, 0);
      }
    }

    float part[4] = {0.f, 0.f, 0.f, 0.f};
    #pragma unroll
    for (int t = 0; t < 10; ++t) {
      #pragma unroll
      for (int r = 0; r < 4; ++r) {
        float h2 = fmaxf(acc2[t][r] + b2v[t], 0.f);
        part[r] += h2 * w3v[t];
      }
    }
    for (int msk = 1; msk < 16; msk <<= 1) {
      #pragma unroll
      for (int r = 0; r < 4; ++r) part[r] += __shfl_xor(part[r], msk);
    }

    if (n16 == 0) {
      #pragma unroll
      for (int r = 0; r < 4; ++r) {
        int gp = gp0 + wrow + tile*16 + quad*4 + r;
        float sc = part[r] + bias3 + ms[mention_ids[gp]] + ms[antecedent_ids[gp]];
        sgrid[seg_ids[gp] * KMAX + offs[gp]] = sc;
      }
    }
  }
}

// ---------- kernel 4: per-group softmax (+epsilon) and full output fill ----------
__global__ __launch_bounds__(128) void softmax_kernel(const float* __restrict__ sgrid,
                                                      const int* __restrict__ lengths,
                                                      float* __restrict__ out) {
  int b = blockIdx.x, t = threadIdx.x;
  if (b == 0) {
    out[t] = (t == 0) ? 1.0f : 1000.0f;
    if (t == 0) out[128] = 1000.0f;
    return;
  }
  int m = b - 1;
  int len = lengths[m];
  float s = (t < len) ? sgrid[m * KMAX + t] : -1e30f;

  __shared__ float redA[2];
  __shared__ float redB[2];

  float v = s;
  #pragma unroll
  for (int o = 32; o >= 1; o >>= 1) v = fmaxf(v, __shfl_xor(v, o));
  if ((t & 63) == 0) redA[t >> 6] = v;
  __syncthreads();
  float mx = fmaxf(fmaxf(redA[0], redA[1]), 0.0f);

  float e = (t < len) ? expf(s - mx) : 0.f;
  float sum = e;
  #pragma unroll
  for (int o = 32; o >= 1; o >>= 1) sum += __shfl_xor(sum, o);
  if ((t & 63) == 0) redB[t >> 6] = sum;
  __syncthreads();

  float eps_e = expf(-mx);
  float denom = redB[0] + redB[1] + eps_e;

  float* row = out + (long)(m + 1) * 129;
  float val;
  if (t < len)       val = e / denom;
  else if (t == len) val = eps_e / denom;
  else               val = 1000.0f;
  row[t] = val;
  if (t == 0) row[128] = (len == KMAX) ? (eps_e / denom) : 1000.0f;
}

extern "C" void kernel_launch(void* const* d_in, const int* in_sizes, int n_in,
                              void* d_out, int out_size, void* d_ws, size_t ws_size,
                              hipStream_t stream) {
  const float* g_i        = (const float*)d_in[0];
  const float* ms         = (const float*)d_in[1];
  const float* dist_emb   = (const float*)d_in[2];
  const float* genre_emb  = (const float*)d_in[3];
  const float* spk_emb    = (const float*)d_in[4];
  const float* W1         = (const float*)d_in[5];
  const float* b1         = (const float*)d_in[6];
  const float* W2         = (const float*)d_in[7];
  const float* b2         = (const float*)d_in[8];
  const float* W3         = (const float*)d_in[9];
  const float* b3         = (const float*)d_in[10];
  const int* mention_ids    = (const int*)d_in[11];
  const int* antecedent_ids = (const int*)d_in[12];
  const int* dist_ids       = (const int*)d_in[13];
  const int* genre_ids      = (const int*)d_in[14];
  const int* spk_ids        = (const int*)d_in[15];
  const int* lengths        = (const int*)d_in[16];
  const int* seg_ids        = (const int*)d_in[17];
  const int* offsets        = (const int*)d_in[18];

  char* ws = (char*)d_ws;
  unsigned char* w1c8  = (unsigned char*)(ws + OFF_W1C8);
  unsigned char* w1ab8 = (unsigned char*)(ws + OFF_W1AB8);
  unsigned char* w2f8  = (unsigned char*)(ws + OFF_W2F8);
  unsigned short* abpre = (unsigned short*)(ws + OFF_ABPRE);
  float* tabs2  = (float*)(ws + OFF_TABS2);
  float* sgrid  = (float*)(ws + OFF_SGRID);
  unsigned char* gf8  = (unsigned char*)(ws + OFF_GF8);
  unsigned char* itab8 = (unsigned char*)(ws + OFF_ITAB);

  const int prepN = S1 + S2 + S3 + S4 + S5 + S6;
  prep_kernel<<<(prepN + 255)/256, 256, 0, stream>>>(W1, W2, g_i,
                                                     dist_emb, genre_emb, spk_emb, b1,
                                                     dist_ids, genre_ids, spk_ids,
                                                     w1c8, w1ab8, w2f8,
                                                     (unsigned*)gf8, tabs2, itab8);
  dim3 gpre(NPOOL/32, 4);
  pre_gemm_kernel<<<gpre, 128, 0, stream>>>(gf8, w1ab8, abpre);
  mlp_kernel<<<P_TOTAL/128, 256, 0, stream>>>(gf8, (const unsigned*)abpre, tabs2, itab8,
                                              w1c8, w2f8, ms,
                                              W3, b2, b3,
                                              mention_ids, antecedent_ids,
                                              seg_ids, offsets, sgrid);
  softmax_kernel<<<MGRP + 1, 128, 0, stream>>>(sgrid, lengths, (float*)d_out);
}

// Round 10
// 243.307 us; speedup vs baseline: 1.0877x; 1.0877x over previous
//
#include <hip/hip_runtime.h>

// Problem constants
#define P_TOTAL 132096
#define NPOOL   4096
#define GDIM    1000
#define HDIM    150
#define MGRP    2048
#define KMAX    128
#define NTILES  (P_TOTAL/128)   // 1032
#define PGRID   768             // 3 blocks/CU x 256 CUs, fully co-resident

typedef __attribute__((ext_vector_type(4))) float f32x4;
typedef __attribute__((ext_vector_type(2))) float f32x2;
typedef __attribute__((ext_vector_type(4))) unsigned int u32x4;

// ---------- workspace layout (bytes) ----------
#define OFF_W1C8   0
#define OFF_W1AB8  163840
#define OFF_W2F8   491520
#define OFF_ABPRE  517120
#define OFF_TABS2  3138560
#define OFF_SGRID  3276800
#define OFF_GF8    4325376
#define OFF_ITAB   8519680

__device__ __forceinline__ short f2bf(float f) {
  union { float f; unsigned u; } v; v.f = f;
  unsigned r = v.u + 0x7FFFu + ((v.u >> 16) & 1u);   // RNE
  return (short)(r >> 16);
}
__device__ __forceinline__ float bf2f(unsigned short s) {
  return __builtin_bit_cast(float, ((unsigned)s) << 16);
}
__device__ __forceinline__ unsigned char f2fp8(float f) {
  int d = __builtin_amdgcn_cvt_pk_fp8_f32(f, 0.f, 0, false);
  return (unsigned char)(d & 0xFF);
}
__device__ __forceinline__ long mk64(unsigned lo, unsigned hi) {
  return (long)(((unsigned long long)hi << 32) | lo);
}

// 16 fp8 x 16 fp8 -> elementwise product, requantized fp8
__device__ __forceinline__ u32x4 fp8prod16(u32x4 m, u32x4 a) {
  u32x4 r;
  #pragma unroll
  for (int d = 0; d < 4; ++d) {
    f32x2 ml = __builtin_amdgcn_cvt_pk_f32_fp8(m[d], false);
    f32x2 mh = __builtin_amdgcn_cvt_pk_f32_fp8(m[d], true);
    f32x2 al = __builtin_amdgcn_cvt_pk_f32_fp8(a[d], false);
    f32x2 ah = __builtin_amdgcn_cvt_pk_f32_fp8(a[d], true);
    f32x2 pl = ml * al, ph = mh * ah;
    int o = __builtin_amdgcn_cvt_pk_fp8_f32(pl[0], pl[1], 0, false);
    o = __builtin_amdgcn_cvt_pk_fp8_f32(ph[0], ph[1], o, true);
    r[d] = (unsigned)o;
  }
  return r;
}

// pack two f32 -> one u32 of 2 bf16 (RNE), single instruction on gfx950
__device__ __forceinline__ unsigned pk_bf16(float lo, float hi) {
  unsigned o;
  asm("v_cvt_pk_bf16_f32 %0, %1, %2" : "=v"(o) : "v"(lo), "v"(hi));
  return o;
}

// ---------- kernel 1: merged prep ----------
#define S1 5120
#define S2 10240
#define S3 800
#define S4 (NPOOL*256)
#define S5 (216*160)
#define S6 P_TOTAL
__global__ __launch_bounds__(256) void prep_kernel(
    const float* __restrict__ W1, const float* __restrict__ W2,
    const float* __restrict__ g_i,
    const float* __restrict__ dist_emb, const float* __restrict__ genre_emb,
    const float* __restrict__ spk_emb, const float* __restrict__ b1,
    const int* __restrict__ did, const int* __restrict__ gid,
    const int* __restrict__ sid,
    unsigned char* __restrict__ w1c8, unsigned char* __restrict__ w1ab8,
    unsigned char* __restrict__ w2f8, unsigned* __restrict__ gf8,
    float* __restrict__ tabs2, unsigned char* __restrict__ itab8) {
  int idx = blockIdx.x * 256 + threadIdx.x;
  if (idx < S1) {                               // w1c8 [c][n][kk], coalesced-in-n reads
    int c = idx / 160, n = idx % 160;
    int s = c >> 1, j = c & 1;
    unsigned dw[8];
    #pragma unroll
    for (int d = 0; d < 8; ++d) {
      unsigned acc = 0;
      #pragma unroll
      for (int b = 0; b < 4; ++b) {
        int kk = d*4 + b;
        int g = kk >> 3, i = kk & 7;
        int q = g ^ ((n >> 2) & 3);             // bank swizzle baked
        int k = s*64 + q*16 + j*8 + i;
        float v = (k < GDIM && n < HDIM) ? W1[(2000 + k)*HDIM + n] : 0.f;
        acc |= ((unsigned)f2fp8(v)) << (8*b);
      }
      dw[d] = acc;
    }
    u32x4 lo = {dw[0], dw[1], dw[2], dw[3]};
    u32x4 hi = {dw[4], dw[5], dw[6], dw[7]};
    *(u32x4*)(w1c8 + c*5120 + n*32)      = lo;
    *(u32x4*)(w1c8 + c*5120 + n*32 + 16) = hi;
  } else if (idx < S1 + S2) {                   // w1ab8 [c][n][kk], BK=128 K-perm
    int i2 = idx - S1;
    int c = i2 / 320, n = i2 % 320;
    int s = c >> 2, j = c & 3;
    unsigned dw[8];
    #pragma unroll
    for (int d = 0; d < 8; ++d) {
      unsigned acc = 0;
      #pragma unroll
      for (int b = 0; b < 4; ++b) {
        int kk = d*4 + b;
        int g = kk >> 3, i = kk & 7;
        int k = s*128 + g*32 + j*8 + i;
        float v = 0.f;
        if (k < GDIM) {
          if (n < HDIM)                 v = W1[k*HDIM + n];
          else if (n >= 160 && n < 310) v = W1[(1000 + k)*HDIM + (n - 160)];
        }
        acc |= ((unsigned)f2fp8(v)) << (8*b);
      }
      dw[d] = acc;
    }
    u32x4 lo = {dw[0], dw[1], dw[2], dw[3]};
    u32x4 hi = {dw[4], dw[5], dw[6], dw[7]};
    *(u32x4*)(w1ab8 + c*10240 + n*32)      = lo;
    *(u32x4*)(w1ab8 + c*10240 + n*32 + 16) = hi;
  } else if (idx < S1 + S2 + S3) {              // w2f8 [c][n][kk], bank swizzle
    int i2 = idx - S1 - S2;
    int c = i2 / 160, n = i2 % 160;
    unsigned dw[8];
    #pragma unroll
    for (int d = 0; d < 8; ++d) {
      unsigned acc = 0;
      #pragma unroll
      for (int b = 0; b < 4; ++b) {
        int kk = d*4 + b;
        int g = kk >> 3, ii = kk & 7;
        int q = g ^ ((n >> 2) & 3);
        int k = c*32 + q*8 + ii;
        float v = (k < HDIM && n < HDIM) ? W2[k*HDIM + n] : 0.f;
        acc |= ((unsigned)f2fp8(v)) << (8*b);
      }
      dw[d] = acc;
    }
    u32x4 lo = {dw[0], dw[1], dw[2], dw[3]};
    u32x4 hi = {dw[4], dw[5], dw[6], dw[7]};
    *(u32x4*)(w2f8 + c*5120 + n*32)      = lo;
    *(u32x4*)(w2f8 + c*5120 + n*32 + 16) = hi;
  } else if (idx < S1 + S2 + S3 + S4) {         // g_i -> fp8 [4096][1024]
    int i = idx - S1 - S2 - S3;
    int row = i >> 8, jd = i & 255;
    int c0 = jd * 4;
    float f0 = (c0     < GDIM) ? g_i[row*GDIM + c0]     : 0.f;
    float f1 = (c0 + 1 < GDIM) ? g_i[row*GDIM + c0 + 1] : 0.f;
    float f2 = (c0 + 2 < GDIM) ? g_i[row*GDIM + c0 + 2] : 0.f;
    float f3 = (c0 + 3 < GDIM) ? g_i[row*GDIM + c0 + 3] : 0.f;
    int d = 0;
    d = __builtin_amdgcn_cvt_pk_fp8_f32(f0, f1, d, false);
    d = __builtin_amdgcn_cvt_pk_fp8_f32(f2, f3, d, true);
    gf8[i] = (unsigned)d;
  } else if (idx < S1 + S2 + S3 + S4 + S5) {    // tabs2: combo phi rows (b1 folded)
    int i = idx - S1 - S2 - S3 - S4;
    int row = i / 160, n = i % 160;
    float acc = 0.f;
    if (n < HDIM) {
      int d = row / 24, g = (row / 3) % 8, sp = row % 3;
      acc = b1[n];
      #pragma unroll
      for (int kk = 0; kk < 20; ++kk) {
        acc += dist_emb [d*20 + kk]  * W1[(3000 + kk)*HDIM + n];
        acc += genre_emb[g*20 + kk]  * W1[(3020 + kk)*HDIM + n];
        acc += spk_emb  [sp*20 + kk] * W1[(3040 + kk)*HDIM + n];
      }
    }
    tabs2[i] = acc;
  } else if (idx < S1 + S2 + S3 + S4 + S5 + S6) {  // itab8: packed combo index
    int p = idx - (S1 + S2 + S3 + S4 + S5);
    itab8[p] = (unsigned char)(did[p]*24 + gid[p]*3 + sid[p]);
  }
}

// ---------- kernel 2: abpre[4096][320](bf16) = g @ [W1a|W1b], fp8 MFMA ----------
__global__ __launch_bounds__(128) void pre_gemm_kernel(
    const unsigned char* __restrict__ gf8, const unsigned char* __restrict__ w1ab8,
    unsigned short* __restrict__ abpre) {
  int wave = threadIdx.x >> 6, lane = threadIdx.x & 63;
  int quad = lane >> 4, n16 = lane & 15;
  int rowbase = blockIdx.x * 32 + wave * 16;
  int colbase = blockIdx.y * 80;

  f32x4 acc[5];
  #pragma unroll
  for (int t = 0; t < 5; ++t) acc[t] = (f32x4){0.f, 0.f, 0.f, 0.f};

  const unsigned char* arow = gf8 + (long)(rowbase + n16) * 1024 + quad*32;

  for (int s = 0; s < 8; ++s) {
    u32x4 Aa = *(const u32x4*)(arow + s*128);
    u32x4 Ab = *(const u32x4*)(arow + s*128 + 16);
    #pragma unroll
    for (int j = 0; j < 4; ++j) {
      long a = (j == 0) ? mk64(Aa[0], Aa[1]) : (j == 1) ? mk64(Aa[2], Aa[3])
             : (j == 2) ? mk64(Ab[0], Ab[1]) : mk64(Ab[2], Ab[3]);
      const unsigned char* bp = w1ab8 + (((s*4 + j)*320 + colbase + n16) * 32 + quad*8);
      #pragma unroll
      for (int t = 0; t < 5; ++t) {
        long b = *(const long*)(bp + t*16*32);
        acc[t] = __builtin_amdgcn_mfma_f32_16x16x32_fp8_fp8(a, b, acc[t], 0, 0, 0);
      }
    }
  }
  #pragma unroll
  for (int t = 0; t < 5; ++t) {
    #pragma unroll
    for (int r = 0; r < 4; ++r) {
      int row = rowbase + quad*4 + r;
      abpre[(long)row * 320 + colbase + t*16 + n16] = (unsigned short)f2bf(acc[t][r]);
    }
  }
}

// ---------- kernel 3: persistent-grid MLP (768 blocks, grid-stride over 1032
// tiles -> no 1-block/CU tail round). Per tile: double-buffered global_load_lds
// staging of A+W1c (best-measured main loop) + cooperative fused extras. ------
__global__ __launch_bounds__(256) void mlp_kernel(
    const unsigned char* __restrict__ gf8,
    const unsigned* __restrict__ abpre32,
    const float* __restrict__ tabs2,
    const unsigned char* __restrict__ itab8,
    const unsigned char* __restrict__ w1c8,
    const unsigned char* __restrict__ w2f8,
    const float* __restrict__ ms,
    const float* __restrict__ W3, const float* __restrict__ b2,
    const float* __restrict__ b3,
    const int* __restrict__ mention_ids, const int* __restrict__ antecedent_ids,
    const int* __restrict__ seg_ids, const int* __restrict__ offs,
    float* __restrict__ sgrid) {

  __shared__ __align__(16) unsigned char lds[53248];

  int tid = threadIdx.x;
  int wave = tid >> 6, lane = tid & 63;
  int quad = lane >> 4, n16 = lane & 15;
  int wrow = wave * 32;

  int jj = (lane & 3) ^ ((lane >> 2) & 3) ^ ((lane >> 4) & 1);
  int srow = lane >> 2;
  int swA = quad ^ (n16 & 3) ^ ((n16 >> 2) & 1);
  int swB = quad ^ ((n16 >> 2) & 3);
  int rowi = lane >> 2, q4 = lane & 3;

  float bias3 = b3[0];
  float w3v[10], b2v[10];
  #pragma unroll
  for (int t = 0; t < 10; ++t) {
    int n = t*16 + n16;
    w3v[t] = (n < HDIM) ? W3[n] : 0.f;
    b2v[t] = (n < HDIM) ? b2[n] : 0.f;
  }

  // grid-stride over tiles: blocks 0..263 do 2 tiles, 264..767 do 1.
  // Trip count depends only on blockIdx -> barriers stay block-uniform.
  for (int tile = blockIdx.x; tile < NTILES; tile += PGRID) {
    int gp0 = tile * 128;

    const unsigned char* pA0 =
        gf8 + (long)mention_ids[gp0 + wave*16 + srow] * 1024 + jj*16;
    const unsigned char* pA1 =
        gf8 + (long)mention_ids[gp0 + (wave + 4)*16 + srow] * 1024 + jj*16;
    const unsigned char* pA2 =
        gf8 + (long)antecedent_ids[gp0 + wave*16 + srow] * 1024 + jj*16;
    const unsigned char* pA3 =
        gf8 + (long)antecedent_ids[gp0 + (wave + 4)*16 + srow] * 1024 + jj*16;
    int dA0 = wave*1024,      dA1 = (wave + 4)*1024;
    int dA2 = 8192 + dA0,     dA3 = 8192 + dA1;

    f32x4 acc0[10], acc1[10];
    #pragma unroll
    for (int t = 0; t < 10; ++t) {
      acc0[t] = (f32x4){0.f, 0.f, 0.f, 0.f};
      acc1[t] = (f32x4){0.f, 0.f, 0.f, 0.f};
    }

    auto issue = [&](int s, int buf) {
      unsigned char* base = lds + buf*26624;
      long so = (long)s * 64;
      __builtin_amdgcn_global_load_lds((const unsigned int*)(pA0 + so),
          (unsigned int*)(base + dA0 + lane*16), 16, 0, 0);
      __builtin_amdgcn_global_load_lds((const unsigned int*)(pA1 + so),
          (unsigned int*)(base + dA1 + lane*16), 16, 0, 0);
      __builtin_amdgcn_global_load_lds((const unsigned int*)(pA2 + so),
          (unsigned int*)(base + dA2 + lane*16), 16, 0, 0);
      __builtin_amdgcn_global_load_lds((const unsigned int*)(pA3 + so),
          (unsigned int*)(base + dA3 + lane*16), 16, 0, 0);
      const unsigned char* wsrc = w1c8 + (long)s*10240;
      __builtin_amdgcn_global_load_lds((const unsigned int*)(wsrc + wave*1024 + (long)lane*16),
          (unsigned int*)(base + 16384 + wave*1024 + lane*16), 16, 0, 0);
      __builtin_amdgcn_global_load_lds((const unsigned int*)(wsrc + (wave+4)*1024 + (long)lane*16),
          (unsigned int*)(base + 16384 + (wave+4)*1024 + lane*16), 16, 0, 0);
      if (wave < 2)
        __builtin_amdgcn_global_load_lds((const unsigned int*)(wsrc + (wave+8)*1024 + (long)lane*16),
            (unsigned int*)(base + 16384 + (wave+8)*1024 + lane*16), 16, 0, 0);
    };

    issue(0, 0);
    for (int s = 0; s < 16; ++s) {
      __syncthreads();
      if (s < 15) issue(s + 1, (s + 1) & 1);
      const unsigned char* cb = lds + (s & 1)*26624;

      u32x4 M0 = *(const u32x4*)(cb + (wrow + n16)*64 + swA*16);
      u32x4 C0 = *(const u32x4*)(cb + 8192 + (wrow + n16)*64 + swA*16);
      u32x4 M1 = *(const u32x4*)(cb + (wrow + 16 + n16)*64 + swA*16);
      u32x4 C1 = *(const u32x4*)(cb + 8192 + (wrow + 16 + n16)*64 + swA*16);
      u32x4 P0 = fp8prod16(M0, C0);
      u32x4 P1 = fp8prod16(M1, C1);

      #pragma unroll
      for (int j = 0; j < 2; ++j) {
        long a0 = (j == 0) ? mk64(P0[0], P0[1]) : mk64(P0[2], P0[3]);
        long a1 = (j == 0) ? mk64(P1[0], P1[1]) : mk64(P1[2], P1[3]);
        const unsigned char* bp = cb + 16384 + j*5120 + n16*32 + swB*8;
        #pragma unroll
        for (int t = 0; t < 10; ++t) {
          long b = *(const long*)(bp + t*512);
          acc0[t] = __builtin_amdgcn_mfma_f32_16x16x32_fp8_fp8(a0, b, acc0[t], 0, 0, 0);
          acc1[t] = __builtin_amdgcn_mfma_f32_16x16x32_fp8_fp8(a1, b, acc1[t], 0, 0, 0);
        }
      }
    }
    __syncthreads();

    // ---- fused extras, cooperative: 4 lanes per pair-row load contiguous
    // chunks, combine to bf16 in wave-private LDS [16][84] u32, then read in
    // MFMA layout.
    unsigned* extw = (unsigned*)(lds + 23552 + wave*5376);
    const unsigned short* ext16 = (const unsigned short*)extw;
    unsigned char* h1w = lds + wave * 5888;   // [32][184] fp8

    #pragma unroll
    for (int p = 0; p < 2; ++p) {
      int gpe = gp0 + wrow + p*16 + rowi;
      int m  = mention_ids[gpe];
      int a  = antecedent_ids[gpe];
      int it = itab8[gpe];
      const u32x4* pm = (const u32x4*)(abpre32 + (long)m*160 + q4*20);
      const u32x4* pa = (const u32x4*)(abpre32 + (long)a*160 + 80 + q4*20);
      const f32x4* tb = (const f32x4*)(tabs2 + (long)it*160 + q4*40);
      #pragma unroll
      for (int k = 0; k < 5; ++k) {
        u32x4 um = pm[k], ua = pa[k];
        f32x4 ta = tb[2*k], tc = tb[2*k + 1];
        u32x4 ov;
        #pragma unroll
        for (int d = 0; d < 4; ++d) {
          float f0 = (d == 0) ? ta[0] : (d == 1) ? ta[2] : (d == 2) ? tc[0] : tc[2];
          float f1 = (d == 0) ? ta[1] : (d == 1) ? ta[3] : (d == 2) ? tc[1] : tc[3];
          float v0 = bf2f((unsigned short)(um[d] & 0xffff))
                   + bf2f((unsigned short)(ua[d] & 0xffff)) + f0;
          float v1 = bf2f((unsigned short)(um[d] >> 16))
                   + bf2f((unsigned short)(ua[d] >> 16)) + f1;
          ov[d] = pk_bf16(v0, v1);
        }
        *(u32x4*)(extw + rowi*84 + q4*20 + 4*k) = ov;
      }
      // consume own wave's ext (wave-private; compiler orders via lgkmcnt)
      #pragma unroll
      for (int r = 0; r < 4; ++r) {
        int lr = quad*4 + r;
        #pragma unroll
        for (int t = 0; t < 10; ++t) {
          int n = t*16 + n16;
          float e = bf2f(ext16[lr*168 + n]);
          float v = ((p == 0) ? acc0[t][r] : acc1[t][r]) + e;
          h1w[(p*16 + lr)*184 + n] = f2fp8(fmaxf(v, 0.f));
        }
      }
      __syncthreads();   // pass isolation (ext reuse) — uniform control flow
    }

    // stage W2 into the now-dead ext region [23552, 49152)
    for (int r = wave; r < 25; r += 4) {
      __builtin_amdgcn_global_load_lds(
          (const unsigned int*)(w2f8 + r*1024 + (long)lane*16),
          (unsigned int*)(lds + 23552 + r*1024), 16, 0, 0);
    }
    __syncthreads();   // W2 landed (barrier drains vmcnt)

    #pragma unroll
    for (int tile2 = 0; tile2 < 2; ++tile2) {
      f32x4 acc2[10];
      #pragma unroll
      for (int t = 0; t < 10; ++t) acc2[t] = (f32x4){0.f, 0.f, 0.f, 0.f};

      #pragma unroll
      for (int c = 0; c < 5; ++c) {
        long a = *(const long*)(h1w + (tile2*16 + n16)*184 + c*32 + quad*8);
        const unsigned char* bp = lds + 23552 + (c*160 + n16)*32 + swB*8;
        #pragma unroll
        for (int t = 0; t < 10; ++t) {
          long b = *(const long*)(bp + t*512);
          acc2[t] = __builtin_amdgcn_mfma_f32_16x16x32_fp8_fp8(a, b, acc2[t], 0, 0, 0);
        }
      }

      float part[4] = {0.f, 0.f, 0.f, 0.f};
      #pragma unroll
      for (int t = 0; t < 10; ++t) {
        #pragma unroll
        for (int r = 0; r < 4; ++r) {
          float h2 = fmaxf(acc2[t][r] + b2v[t], 0.f);
          part[r] += h2 * w3v[t];
        }
      }
      for (int msk = 1; msk < 16; msk <<= 1) {
        #pragma unroll
        for (int r = 0; r < 4; ++r) part[r] += __shfl_xor(part[r], msk);
      }

      if (n16 == 0) {
        #pragma unroll
        for (int r = 0; r < 4; ++r) {
          int gp = gp0 + wrow + tile2*16 + quad*4 + r;
          float sc = part[r] + bias3 + ms[mention_ids[gp]] + ms[antecedent_ids[gp]];
          sgrid[seg_ids[gp] * KMAX + offs[gp]] = sc;
        }
      }
    }
    __syncthreads();   // sequence LDS overlay reuse before next tile's staging
  }
}

// ---------- kernel 4: per-group softmax (+epsilon) and full output fill ----------
__global__ __launch_bounds__(128) void softmax_kernel(const float* __restrict__ sgrid,
                                                      const int* __restrict__ lengths,
                                                      float* __restrict__ out) {
  int b = blockIdx.x, t = threadIdx.x;
  if (b == 0) {
    out[t] = (t == 0) ? 1.0f : 1000.0f;
    if (t == 0) out[128] = 1000.0f;
    return;
  }
  int m = b - 1;
  int len = lengths[m];
  float s = (t < len) ? sgrid[m * KMAX + t] : -1e30f;

  __shared__ float redA[2];
  __shared__ float redB[2];

  float v = s;
  #pragma unroll
  for (int o = 32; o >= 1; o >>= 1) v = fmaxf(v, __shfl_xor(v, o));
  if ((t & 63) == 0) redA[t >> 6] = v;
  __syncthreads();
  float mx = fmaxf(fmaxf(redA[0], redA[1]), 0.0f);

  float e = (t < len) ? expf(s - mx) : 0.f;
  float sum = e;
  #pragma unroll
  for (int o = 32; o >= 1; o >>= 1) sum += __shfl_xor(sum, o);
  if ((t & 63) == 0) redB[t >> 6] = sum;
  __syncthreads();

  float eps_e = expf(-mx);
  float denom = redB[0] + redB[1] + eps_e;

  float* row = out + (long)(m + 1) * 129;
  float val;
  if (t < len)       val = e / denom;
  else if (t == len) val = eps_e / denom;
  else               val = 1000.0f;
  row[t] = val;
  if (t == 0) row[128] = (len == KMAX) ? (eps_e / denom) : 1000.0f;
}

extern "C" void kernel_launch(void* const* d_in, const int* in_sizes, int n_in,
                              void* d_out, int out_size, void* d_ws, size_t ws_size,
                              hipStream_t stream) {
  const float* g_i        = (const float*)d_in[0];
  const float* ms         = (const float*)d_in[1];
  const float* dist_emb   = (const float*)d_in[2];
  const float* genre_emb  = (const float*)d_in[3];
  const float* spk_emb    = (const float*)d_in[4];
  const float* W1         = (const float*)d_in[5];
  const float* b1         = (const float*)d_in[6];
  const float* W2         = (const float*)d_in[7];
  const float* b2         = (const float*)d_in[8];
  const float* W3         = (const float*)d_in[9];
  const float* b3         = (const float*)d_in[10];
  const int* mention_ids    = (const int*)d_in[11];
  const int* antecedent_ids = (const int*)d_in[12];
  const int* dist_ids       = (const int*)d_in[13];
  const int* genre_ids      = (const int*)d_in[14];
  const int* spk_ids        = (const int*)d_in[15];
  const int* lengths        = (const int*)d_in[16];
  const int* seg_ids        = (const int*)d_in[17];
  const int* offsets        = (const int*)d_in[18];

  char* ws = (char*)d_ws;
  unsigned char* w1c8  = (unsigned char*)(ws + OFF_W1C8);
  unsigned char* w1ab8 = (unsigned char*)(ws + OFF_W1AB8);
  unsigned char* w2f8  = (unsigned char*)(ws + OFF_W2F8);
  unsigned short* abpre = (unsigned short*)(ws + OFF_ABPRE);
  float* tabs2  = (float*)(ws + OFF_TABS2);
  float* sgrid  = (float*)(ws + OFF_SGRID);
  unsigned char* gf8  = (unsigned char*)(ws + OFF_GF8);
  unsigned char* itab8 = (unsigned char*)(ws + OFF_ITAB);

  const int prepN = S1 + S2 + S3 + S4 + S5 + S6;
  prep_kernel<<<(prepN + 255)/256, 256, 0, stream>>>(W1, W2, g_i,
                                                     dist_emb, genre_emb, spk_emb, b1,
                                                     dist_ids, genre_ids, spk_ids,
                                                     w1c8, w1ab8, w2f8,
                                                     (unsigned*)gf8, tabs2, itab8);
  dim3 gpre(NPOOL/32, 4);
  pre_gemm_kernel<<<gpre, 128, 0, stream>>>(gf8, w1ab8, abpre);
  mlp_kernel<<<PGRID, 256, 0, stream>>>(gf8, (const unsigned*)abpre, tabs2, itab8,
                                        w1c8, w2f8, ms,
                                        W3, b2, b3,
                                        mention_ids, antecedent_ids,
                                        seg_ids, offsets, sgrid);
  softmax_kernel<<<MGRP + 1, 128, 0, stream>>>(sgrid, lengths, (float*)d_out);
}

// Round 11
// 199.655 us; speedup vs baseline: 1.3256x; 1.2186x over previous
//
#include <hip/hip_runtime.h>

// Problem constants
#define P_TOTAL 132096
#define NPOOL   4096
#define GDIM    1000
#define HDIM    150
#define MGRP    2048
#define KMAX    128

typedef __attribute__((ext_vector_type(4))) float f32x4;
typedef __attribute__((ext_vector_type(2))) float f32x2;
typedef __attribute__((ext_vector_type(4))) unsigned int u32x4;

// ---------- workspace layout (bytes) ----------
#define OFF_W1C8   0
#define OFF_W1AB8  163840
#define OFF_W2F8   491520
#define OFF_ABPRE  517120
#define OFF_TABS2  3138560
#define OFF_SGRID  3276800
#define OFF_GF8    4325376
#define OFF_ITAB   8519680

__device__ __forceinline__ short f2bf(float f) {
  union { float f; unsigned u; } v; v.f = f;
  unsigned r = v.u + 0x7FFFu + ((v.u >> 16) & 1u);   // RNE
  return (short)(r >> 16);
}
__device__ __forceinline__ float bf2f(unsigned short s) {
  return __builtin_bit_cast(float, ((unsigned)s) << 16);
}
__device__ __forceinline__ unsigned char f2fp8(float f) {
  int d = __builtin_amdgcn_cvt_pk_fp8_f32(f, 0.f, 0, false);
  return (unsigned char)(d & 0xFF);
}
__device__ __forceinline__ long mk64(unsigned lo, unsigned hi) {
  return (long)(((unsigned long long)hi << 32) | lo);
}

// 16 fp8 x 16 fp8 -> elementwise product, requantized fp8
__device__ __forceinline__ u32x4 fp8prod16(u32x4 m, u32x4 a) {
  u32x4 r;
  #pragma unroll
  for (int d = 0; d < 4; ++d) {
    f32x2 ml = __builtin_amdgcn_cvt_pk_f32_fp8(m[d], false);
    f32x2 mh = __builtin_amdgcn_cvt_pk_f32_fp8(m[d], true);
    f32x2 al = __builtin_amdgcn_cvt_pk_f32_fp8(a[d], false);
    f32x2 ah = __builtin_amdgcn_cvt_pk_f32_fp8(a[d], true);
    f32x2 pl = ml * al, ph = mh * ah;
    int o = __builtin_amdgcn_cvt_pk_fp8_f32(pl[0], pl[1], 0, false);
    o = __builtin_amdgcn_cvt_pk_fp8_f32(ph[0], ph[1], o, true);
    r[d] = (unsigned)o;
  }
  return r;
}

// ---------- kernel 1: merged prep ----------
#define S1 5120
#define S2 10240
#define S3 800
#define S4 (NPOOL*256)
#define S5 (216*160)
#define S6 P_TOTAL
__global__ __launch_bounds__(256) void prep_kernel(
    const float* __restrict__ W1, const float* __restrict__ W2,
    const float* __restrict__ g_i,
    const float* __restrict__ dist_emb, const float* __restrict__ genre_emb,
    const float* __restrict__ spk_emb, const float* __restrict__ b1,
    const int* __restrict__ did, const int* __restrict__ gid,
    const int* __restrict__ sid,
    unsigned char* __restrict__ w1c8, unsigned char* __restrict__ w1ab8,
    unsigned char* __restrict__ w2f8, unsigned* __restrict__ gf8,
    float* __restrict__ tabs2, unsigned char* __restrict__ itab8) {
  int idx = blockIdx.x * 256 + threadIdx.x;
  if (idx < S1) {                               // w1c8 [c][n][kk], coalesced-in-n reads
    int c = idx / 160, n = idx % 160;
    int s = c >> 1, j = c & 1;
    unsigned dw[8];
    #pragma unroll
    for (int d = 0; d < 8; ++d) {
      unsigned acc = 0;
      #pragma unroll
      for (int b = 0; b < 4; ++b) {
        int kk = d*4 + b;
        int g = kk >> 3, i = kk & 7;
        int q = g ^ ((n >> 2) & 3);             // bank swizzle baked
        int k = s*64 + q*16 + j*8 + i;
        float v = (k < GDIM && n < HDIM) ? W1[(2000 + k)*HDIM + n] : 0.f;
        acc |= ((unsigned)f2fp8(v)) << (8*b);
      }
      dw[d] = acc;
    }
    u32x4 lo = {dw[0], dw[1], dw[2], dw[3]};
    u32x4 hi = {dw[4], dw[5], dw[6], dw[7]};
    *(u32x4*)(w1c8 + c*5120 + n*32)      = lo;
    *(u32x4*)(w1c8 + c*5120 + n*32 + 16) = hi;
  } else if (idx < S1 + S2) {                   // w1ab8 [c][n][kk], BK=128 K-perm
    int i2 = idx - S1;
    int c = i2 / 320, n = i2 % 320;
    int s = c >> 2, j = c & 3;
    unsigned dw[8];
    #pragma unroll
    for (int d = 0; d < 8; ++d) {
      unsigned acc = 0;
      #pragma unroll
      for (int b = 0; b < 4; ++b) {
        int kk = d*4 + b;
        int g = kk >> 3, i = kk & 7;
        int k = s*128 + g*32 + j*8 + i;
        float v = 0.f;
        if (k < GDIM) {
          if (n < HDIM)                 v = W1[k*HDIM + n];
          else if (n >= 160 && n < 310) v = W1[(1000 + k)*HDIM + (n - 160)];
        }
        acc |= ((unsigned)f2fp8(v)) << (8*b);
      }
      dw[d] = acc;
    }
    u32x4 lo = {dw[0], dw[1], dw[2], dw[3]};
    u32x4 hi = {dw[4], dw[5], dw[6], dw[7]};
    *(u32x4*)(w1ab8 + c*10240 + n*32)      = lo;
    *(u32x4*)(w1ab8 + c*10240 + n*32 + 16) = hi;
  } else if (idx < S1 + S2 + S3) {              // w2f8 [c][n][kk], bank swizzle
    int i2 = idx - S1 - S2;
    int c = i2 / 160, n = i2 % 160;
    unsigned dw[8];
    #pragma unroll
    for (int d = 0; d < 8; ++d) {
      unsigned acc = 0;
      #pragma unroll
      for (int b = 0; b < 4; ++b) {
        int kk = d*4 + b;
        int g = kk >> 3, ii = kk & 7;
        int q = g ^ ((n >> 2) & 3);
        int k = c*32 + q*8 + ii;
        float v = (k < HDIM && n < HDIM) ? W2[k*HDIM + n] : 0.f;
        acc |= ((unsigned)f2fp8(v)) << (8*b);
      }
      dw[d] = acc;
    }
    u32x4 lo = {dw[0], dw[1], dw[2], dw[3]};
    u32x4 hi = {dw[4], dw[5], dw[6], dw[7]};
    *(u32x4*)(w2f8 + c*5120 + n*32)      = lo;
    *(u32x4*)(w2f8 + c*5120 + n*32 + 16) = hi;
  } else if (idx < S1 + S2 + S3 + S4) {         // g_i -> fp8 [4096][1024]
    int i = idx - S1 - S2 - S3;
    int row = i >> 8, jd = i & 255;
    int c0 = jd * 4;
    float f0 = (c0     < GDIM) ? g_i[row*GDIM + c0]     : 0.f;
    float f1 = (c0 + 1 < GDIM) ? g_i[row*GDIM + c0 + 1] : 0.f;
    float f2 = (c0 + 2 < GDIM) ? g_i[row*GDIM + c0 + 2] : 0.f;
    float f3 = (c0 + 3 < GDIM) ? g_i[row*GDIM + c0 + 3] : 0.f;
    int d = 0;
    d = __builtin_amdgcn_cvt_pk_fp8_f32(f0, f1, d, false);
    d = __builtin_amdgcn_cvt_pk_fp8_f32(f2, f3, d, true);
    gf8[i] = (unsigned)d;
  } else if (idx < S1 + S2 + S3 + S4 + S5) {    // tabs2: combo phi rows (b1 folded)
    int i = idx - S1 - S2 - S3 - S4;
    int row = i / 160, n = i % 160;
    float acc = 0.f;
    if (n < HDIM) {
      int d = row / 24, g = (row / 3) % 8, sp = row % 3;
      acc = b1[n];
      #pragma unroll
      for (int kk = 0; kk < 20; ++kk) {
        acc += dist_emb [d*20 + kk]  * W1[(3000 + kk)*HDIM + n];
        acc += genre_emb[g*20 + kk]  * W1[(3020 + kk)*HDIM + n];
        acc += spk_emb  [sp*20 + kk] * W1[(3040 + kk)*HDIM + n];
      }
    }
    tabs2[i] = acc;
  } else if (idx < S1 + S2 + S3 + S4 + S5 + S6) {  // itab8: packed combo index
    int p = idx - (S1 + S2 + S3 + S4 + S5);
    itab8[p] = (unsigned char)(did[p]*24 + gid[p]*3 + sid[p]);
  }
}

// ---------- kernel 2: abpre[4096][320](bf16) = g @ [W1a|W1b], fp8 MFMA ----------
__global__ __launch_bounds__(128) void pre_gemm_kernel(
    const unsigned char* __restrict__ gf8, const unsigned char* __restrict__ w1ab8,
    unsigned short* __restrict__ abpre) {
  int wave = threadIdx.x >> 6, lane = threadIdx.x & 63;
  int quad = lane >> 4, n16 = lane & 15;
  int rowbase = blockIdx.x * 32 + wave * 16;
  int colbase = blockIdx.y * 80;

  f32x4 acc[5];
  #pragma unroll
  for (int t = 0; t < 5; ++t) acc[t] = (f32x4){0.f, 0.f, 0.f, 0.f};

  const unsigned char* arow = gf8 + (long)(rowbase + n16) * 1024 + quad*32;

  for (int s = 0; s < 8; ++s) {
    u32x4 Aa = *(const u32x4*)(arow + s*128);
    u32x4 Ab = *(const u32x4*)(arow + s*128 + 16);
    #pragma unroll
    for (int j = 0; j < 4; ++j) {
      long a = (j == 0) ? mk64(Aa[0], Aa[1]) : (j == 1) ? mk64(Aa[2], Aa[3])
             : (j == 2) ? mk64(Ab[0], Ab[1]) : mk64(Ab[2], Ab[3]);
      const unsigned char* bp = w1ab8 + (((s*4 + j)*320 + colbase + n16) * 32 + quad*8);
      #pragma unroll
      for (int t = 0; t < 5; ++t) {
        long b = *(const long*)(bp + t*16*32);
        acc[t] = __builtin_amdgcn_mfma_f32_16x16x32_fp8_fp8(a, b, acc[t], 0, 0, 0);
      }
    }
  }
  #pragma unroll
  for (int t = 0; t < 5; ++t) {
    #pragma unroll
    for (int r = 0; r < 4; ++r) {
      int row = rowbase + quad*4 + r;
      abpre[(long)row * 320 + colbase + t*16 + n16] = (unsigned short)f2bf(acc[t][r]);
    }
  }
}

// ---------- kernel 3: double-buffered staged MLP (r12 structure) with the
// extras term fused into the epilogue (abpre/tabs2 are L2-hot; no HBM stream) --
__global__ __launch_bounds__(256) void mlp_kernel(
    const unsigned char* __restrict__ gf8,
    const unsigned short* __restrict__ abpre,
    const float* __restrict__ tabs2,
    const unsigned char* __restrict__ itab8,
    const unsigned char* __restrict__ w1c8,
    const unsigned char* __restrict__ w2f8,
    const float* __restrict__ ms,
    const float* __restrict__ W3, const float* __restrict__ b2,
    const float* __restrict__ b3,
    const int* __restrict__ mention_ids, const int* __restrict__ antecedent_ids,
    const int* __restrict__ seg_ids, const int* __restrict__ offs,
    float* __restrict__ sgrid) {

  __shared__ __align__(16) unsigned char lds[53248];

  int tid = threadIdx.x;
  int wave = tid >> 6, lane = tid & 63;
  int quad = lane >> 4, n16 = lane & 15;
  int lp0 = blockIdx.x * 128;
  int gp0 = lp0;
  int wrow = wave * 32;

  int jj = (lane & 3) ^ ((lane >> 2) & 3) ^ ((lane >> 4) & 1);
  int srow = lane >> 2;
  int swA = quad ^ (n16 & 3) ^ ((n16 >> 2) & 1);
  int swB = quad ^ ((n16 >> 2) & 3);

  const unsigned char* pA0 =
      gf8 + (long)mention_ids[gp0 + wave*16 + srow] * 1024 + jj*16;
  const unsigned char* pA1 =
      gf8 + (long)mention_ids[gp0 + (wave + 4)*16 + srow] * 1024 + jj*16;
  const unsigned char* pA2 =
      gf8 + (long)antecedent_ids[gp0 + wave*16 + srow] * 1024 + jj*16;
  const unsigned char* pA3 =
      gf8 + (long)antecedent_ids[gp0 + (wave + 4)*16 + srow] * 1024 + jj*16;
  int dA0 = wave*1024,      dA1 = (wave + 4)*1024;
  int dA2 = 8192 + dA0,     dA3 = 8192 + dA1;

  f32x4 acc0[10], acc1[10];
  #pragma unroll
  for (int t = 0; t < 10; ++t) {
    acc0[t] = (f32x4){0.f, 0.f, 0.f, 0.f};
    acc1[t] = (f32x4){0.f, 0.f, 0.f, 0.f};
  }

  auto issue = [&](int s, int buf) {
    unsigned char* base = lds + buf*26624;
    long so = (long)s * 64;
    __builtin_amdgcn_global_load_lds((const unsigned int*)(pA0 + so),
        (unsigned int*)(base + dA0 + lane*16), 16, 0, 0);
    __builtin_amdgcn_global_load_lds((const unsigned int*)(pA1 + so),
        (unsigned int*)(base + dA1 + lane*16), 16, 0, 0);
    __builtin_amdgcn_global_load_lds((const unsigned int*)(pA2 + so),
        (unsigned int*)(base + dA2 + lane*16), 16, 0, 0);
    __builtin_amdgcn_global_load_lds((const unsigned int*)(pA3 + so),
        (unsigned int*)(base + dA3 + lane*16), 16, 0, 0);
    const unsigned char* wsrc = w1c8 + (long)s*10240;
    __builtin_amdgcn_global_load_lds((const unsigned int*)(wsrc + wave*1024 + (long)lane*16),
        (unsigned int*)(base + 16384 + wave*1024 + lane*16), 16, 0, 0);
    __builtin_amdgcn_global_load_lds((const unsigned int*)(wsrc + (wave+4)*1024 + (long)lane*16),
        (unsigned int*)(base + 16384 + (wave+4)*1024 + lane*16), 16, 0, 0);
    if (wave < 2)
      __builtin_amdgcn_global_load_lds((const unsigned int*)(wsrc + (wave+8)*1024 + (long)lane*16),
          (unsigned int*)(base + 16384 + (wave+8)*1024 + lane*16), 16, 0, 0);
  };

  issue(0, 0);
  for (int s = 0; s < 16; ++s) {
    __syncthreads();
    if (s < 15) issue(s + 1, (s + 1) & 1);
    const unsigned char* cb = lds + (s & 1)*26624;

    u32x4 M0 = *(const u32x4*)(cb + (wrow + n16)*64 + swA*16);
    u32x4 C0 = *(const u32x4*)(cb + 8192 + (wrow + n16)*64 + swA*16);
    u32x4 M1 = *(const u32x4*)(cb + (wrow + 16 + n16)*64 + swA*16);
    u32x4 C1 = *(const u32x4*)(cb + 8192 + (wrow + 16 + n16)*64 + swA*16);
    u32x4 P0 = fp8prod16(M0, C0);
    u32x4 P1 = fp8prod16(M1, C1);

    #pragma unroll
    for (int j = 0; j < 2; ++j) {
      long a0 = (j == 0) ? mk64(P0[0], P0[1]) : mk64(P0[2], P0[3]);
      long a1 = (j == 0) ? mk64(P1[0], P1[1]) : mk64(P1[2], P1[3]);
      const unsigned char* bp = cb + 16384 + j*5120 + n16*32 + swB*8;
      #pragma unroll
      for (int t = 0; t < 10; ++t) {
        long b = *(const long*)(bp + t*512);
        acc0[t] = __builtin_amdgcn_mfma_f32_16x16x32_fp8_fp8(a0, b, acc0[t], 0, 0, 0);
        acc1[t] = __builtin_amdgcn_mfma_f32_16x16x32_fp8_fp8(a1, b, acc1[t], 0, 0, 0);
      }
    }
  }
  __syncthreads();

  for (int r = wave; r < 25; r += 4) {
    __builtin_amdgcn_global_load_lds(
        (const unsigned int*)(w2f8 + r*1024 + (long)lane*16),
        (unsigned int*)(lds + 26624 + r*1024), 16, 0, 0);
  }

  // epilogue: extras computed on the fly from abpre (L2-hot) + tabs2 + itab8
  unsigned char* h1w = lds + wave * 5888;   // [32][184] fp8
  #pragma unroll
  for (int r = 0; r < 4; ++r) {
    int row0 = quad*4 + r;
    int gpA = gp0 + wrow + row0;        // rows for acc0
    int gpB = gpA + 16;                 // rows for acc1
    const unsigned short* pmA = abpre + (long)mention_ids[gpA]*320;
    const unsigned short* paA = abpre + (long)antecedent_ids[gpA]*320 + 160;
    const float*          tbA = tabs2 + (long)itab8[gpA]*160;
    const unsigned short* pmB = abpre + (long)mention_ids[gpB]*320;
    const unsigned short* paB = abpre + (long)antecedent_ids[gpB]*320 + 160;
    const float*          tbB = tabs2 + (long)itab8[gpB]*160;
    #pragma unroll
    for (int t = 0; t < 10; ++t) {
      int n = t*16 + n16;
      float v0 = acc0[t][r] + bf2f(pmA[n]) + bf2f(paA[n]) + tbA[n];
      float v1 = acc1[t][r] + bf2f(pmB[n]) + bf2f(paB[n]) + tbB[n];
      h1w[row0*184 + n]        = f2fp8(fmaxf(v0, 0.f));
      h1w[(16 + row0)*184 + n] = f2fp8(fmaxf(v1, 0.f));
    }
  }
  __syncthreads();

  float bias3 = b3[0];
  float w3v[10], b2v[10];
  #pragma unroll
  for (int t = 0; t < 10; ++t) {
    int n = t*16 + n16;
    w3v[t] = (n < HDIM) ? W3[n] : 0.f;
    b2v[t] = (n < HDIM) ? b2[n] : 0.f;
  }

  #pragma unroll
  for (int tile = 0; tile < 2; ++tile) {
    f32x4 acc2[10];
    #pragma unroll
    for (int t = 0; t < 10; ++t) acc2[t] = (f32x4){0.f, 0.f, 0.f, 0.f};

    #pragma unroll
    for (int c = 0; c < 5; ++c) {
      long a = *(const long*)(h1w + (tile*16 + n16)*184 + c*32 + quad*8);
      const unsigned char* bp = lds + 26624 + (c*160 + n16)*32 + swB*8;
      #pragma unroll
      for (int t = 0; t < 10; ++t) {
        long b = *(const long*)(bp + t*512);
        acc2[t] = __builtin_amdgcn_mfma_f32_16x16x32_fp8_fp8(a, b, acc2[t], 0, 0, 0);
      }
    }

    float part[4] = {0.f, 0.f, 0.f, 0.f};
    #pragma unroll
    for (int t = 0; t < 10; ++t) {
      #pragma unroll
      for (int r = 0; r < 4; ++r) {
        float h2 = fmaxf(acc2[t][r] + b2v[t], 0.f);
        part[r] += h2 * w3v[t];
      }
    }
    for (int msk = 1; msk < 16; msk <<= 1) {
      #pragma unroll
      for (int r = 0; r < 4; ++r) part[r] += __shfl_xor(part[r], msk);
    }

    if (n16 == 0) {
      #pragma unroll
      for (int r = 0; r < 4; ++r) {
        int gp = gp0 + wrow + tile*16 + quad*4 + r;
        float sc = part[r] + bias3 + ms[mention_ids[gp]] + ms[antecedent_ids[gp]];
        sgrid[seg_ids[gp] * KMAX + offs[gp]] = sc;
      }
    }
  }
}

// ---------- kernel 4: per-group softmax (+epsilon) and full output fill ----------
__global__ __launch_bounds__(128) void softmax_kernel(const float* __restrict__ sgrid,
                                                      const int* __restrict__ lengths,
                                                      float* __restrict__ out) {
  int b = blockIdx.x, t = threadIdx.x;
  if (b == 0) {
    out[t] = (t == 0) ? 1.0f : 1000.0f;
    if (t == 0) out[128] = 1000.0f;
    return;
  }
  int m = b - 1;
  int len = lengths[m];
  float s = (t < len) ? sgrid[m * KMAX + t] : -1e30f;

  __shared__ float redA[2];
  __shared__ float redB[2];

  float v = s;
  #pragma unroll
  for (int o = 32; o >= 1; o >>= 1) v = fmaxf(v, __shfl_xor(v, o));
  if ((t & 63) == 0) redA[t >> 6] = v;
  __syncthreads();
  float mx = fmaxf(fmaxf(redA[0], redA[1]), 0.0f);

  float e = (t < len) ? expf(s - mx) : 0.f;
  float sum = e;
  #pragma unroll
  for (int o = 32; o >= 1; o >>= 1) sum += __shfl_xor(sum, o);
  if ((t & 63) == 0) redB[t >> 6] = sum;
  __syncthreads();

  float eps_e = expf(-mx);
  float denom = redB[0] + redB[1] + eps_e;

  float* row = out + (long)(m + 1) * 129;
  float val;
  if (t < len)       val = e / denom;
  else if (t == len) val = eps_e / denom;
  else               val = 1000.0f;
  row[t] = val;
  if (t == 0) row[128] = (len == KMAX) ? (eps_e / denom) : 1000.0f;
}

extern "C" void kernel_launch(void* const* d_in, const int* in_sizes, int n_in,
                              void* d_out, int out_size, void* d_ws, size_t ws_size,
                              hipStream_t stream) {
  const float* g_i        = (const float*)d_in[0];
  const float* ms         = (const float*)d_in[1];
  const float* dist_emb   = (const float*)d_in[2];
  const float* genre_emb  = (const float*)d_in[3];
  const float* spk_emb    = (const float*)d_in[4];
  const float* W1         = (const float*)d_in[5];
  const float* b1         = (const float*)d_in[6];
  const float* W2         = (const float*)d_in[7];
  const float* b2         = (const float*)d_in[8];
  const float* W3         = (const float*)d_in[9];
  const float* b3         = (const float*)d_in[10];
  const int* mention_ids    = (const int*)d_in[11];
  const int* antecedent_ids = (const int*)d_in[12];
  const int* dist_ids       = (const int*)d_in[13];
  const int* genre_ids      = (const int*)d_in[14];
  const int* spk_ids        = (const int*)d_in[15];
  const int* lengths        = (const int*)d_in[16];
  const int* seg_ids        = (const int*)d_in[17];
  const int* offsets        = (const int*)d_in[18];

  char* ws = (char*)d_ws;
  unsigned char* w1c8  = (unsigned char*)(ws + OFF_W1C8);
  unsigned char* w1ab8 = (unsigned char*)(ws + OFF_W1AB8);
  unsigned char* w2f8  = (unsigned char*)(ws + OFF_W2F8);
  unsigned short* abpre = (unsigned short*)(ws + OFF_ABPRE);
  float* tabs2  = (float*)(ws + OFF_TABS2);
  float* sgrid  = (float*)(ws + OFF_SGRID);
  unsigned char* gf8  = (unsigned char*)(ws + OFF_GF8);
  unsigned char* itab8 = (unsigned char*)(ws + OFF_ITAB);

  const int prepN = S1 + S2 + S3 + S4 + S5 + S6;
  prep_kernel<<<(prepN + 255)/256, 256, 0, stream>>>(W1, W2, g_i,
                                                     dist_emb, genre_emb, spk_emb, b1,
                                                     dist_ids, genre_ids, spk_ids,
                                                     w1c8, w1ab8, w2f8,
                                                     (unsigned*)gf8, tabs2, itab8);
  dim3 gpre(NPOOL/32, 4);
  pre_gemm_kernel<<<gpre, 128, 0, stream>>>(gf8, w1ab8, abpre);
  mlp_kernel<<<P_TOTAL/128, 256, 0, stream>>>(gf8, abpre, tabs2, itab8,
                                              w1c8, w2f8, ms,
                                              W3, b2, b3,
                                              mention_ids, antecedent_ids,
                                              seg_ids, offsets, sgrid);
  softmax_kernel<<<MGRP + 1, 128, 0, stream>>>(sgrid, lengths, (float*)d_out);
}

// Round 12
// 198.828 us; speedup vs baseline: 1.3311x; 1.0042x over previous
//
#include <hip/hip_runtime.h>

// Problem constants
#define P_TOTAL 132096
#define NPOOL   4096
#define GDIM    1000
#define HDIM    150
#define MGRP    2048
#define KMAX    128

typedef __attribute__((ext_vector_type(4))) float f32x4;
typedef __attribute__((ext_vector_type(2))) float f32x2;
typedef __attribute__((ext_vector_type(4))) unsigned int u32x4;

// ---------- workspace layout (bytes) ----------
#define OFF_W1C8   0
#define OFF_W1AB8  163840
#define OFF_W2F8   491520
#define OFF_ABPRE  517120
#define OFF_TABS2  3138560
#define OFF_SGRID  3276800
#define OFF_GF8    4325376
#define OFF_ITAB   8519680

__device__ __forceinline__ short f2bf(float f) {
  union { float f; unsigned u; } v; v.f = f;
  unsigned r = v.u + 0x7FFFu + ((v.u >> 16) & 1u);   // RNE
  return (short)(r >> 16);
}
__device__ __forceinline__ float bf2f(unsigned short s) {
  return __builtin_bit_cast(float, ((unsigned)s) << 16);
}
__device__ __forceinline__ unsigned char f2fp8(float f) {
  int d = __builtin_amdgcn_cvt_pk_fp8_f32(f, 0.f, 0, false);
  return (unsigned char)(d & 0xFF);
}
__device__ __forceinline__ long mk64(unsigned lo, unsigned hi) {
  return (long)(((unsigned long long)hi << 32) | lo);
}

// 16 fp8 x 16 fp8 -> elementwise product, requantized fp8
__device__ __forceinline__ u32x4 fp8prod16(u32x4 m, u32x4 a) {
  u32x4 r;
  #pragma unroll
  for (int d = 0; d < 4; ++d) {
    f32x2 ml = __builtin_amdgcn_cvt_pk_f32_fp8(m[d], false);
    f32x2 mh = __builtin_amdgcn_cvt_pk_f32_fp8(m[d], true);
    f32x2 al = __builtin_amdgcn_cvt_pk_f32_fp8(a[d], false);
    f32x2 ah = __builtin_amdgcn_cvt_pk_f32_fp8(a[d], true);
    f32x2 pl = ml * al, ph = mh * ah;
    int o = __builtin_amdgcn_cvt_pk_fp8_f32(pl[0], pl[1], 0, false);
    o = __builtin_amdgcn_cvt_pk_fp8_f32(ph[0], ph[1], o, true);
    r[d] = (unsigned)o;
  }
  return r;
}

// ---------- kernel 1: merged prep ----------
#define S1 5120
#define S2 10240
#define S3 800
#define S4 (NPOOL*256)
#define S5 (216*160)
#define S6 P_TOTAL
__global__ __launch_bounds__(256) void prep_kernel(
    const float* __restrict__ W1, const float* __restrict__ W2,
    const float* __restrict__ g_i,
    const float* __restrict__ dist_emb, const float* __restrict__ genre_emb,
    const float* __restrict__ spk_emb, const float* __restrict__ b1,
    const int* __restrict__ did, const int* __restrict__ gid,
    const int* __restrict__ sid,
    unsigned char* __restrict__ w1c8, unsigned char* __restrict__ w1ab8,
    unsigned char* __restrict__ w2f8, unsigned* __restrict__ gf8,
    float* __restrict__ tabs2, unsigned char* __restrict__ itab8) {
  int idx = blockIdx.x * 256 + threadIdx.x;
  if (idx < S1) {                               // w1c8 [c][n][kk], coalesced-in-n reads
    int c = idx / 160, n = idx % 160;
    int s = c >> 1, j = c & 1;
    unsigned dw[8];
    #pragma unroll
    for (int d = 0; d < 8; ++d) {
      unsigned acc = 0;
      #pragma unroll
      for (int b = 0; b < 4; ++b) {
        int kk = d*4 + b;
        int g = kk >> 3, i = kk & 7;
        int q = g ^ ((n >> 2) & 3);             // bank swizzle baked
        int k = s*64 + q*16 + j*8 + i;
        float v = (k < GDIM && n < HDIM) ? W1[(2000 + k)*HDIM + n] : 0.f;
        acc |= ((unsigned)f2fp8(v)) << (8*b);
      }
      dw[d] = acc;
    }
    u32x4 lo = {dw[0], dw[1], dw[2], dw[3]};
    u32x4 hi = {dw[4], dw[5], dw[6], dw[7]};
    *(u32x4*)(w1c8 + c*5120 + n*32)      = lo;
    *(u32x4*)(w1c8 + c*5120 + n*32 + 16) = hi;
  } else if (idx < S1 + S2) {                   // w1ab8 [c][n][kk], BK=128 K-perm
    int i2 = idx - S1;
    int c = i2 / 320, n = i2 % 320;
    int s = c >> 2, j = c & 3;
    unsigned dw[8];
    #pragma unroll
    for (int d = 0; d < 8; ++d) {
      unsigned acc = 0;
      #pragma unroll
      for (int b = 0; b < 4; ++b) {
        int kk = d*4 + b;
        int g = kk >> 3, i = kk & 7;
        int k = s*128 + g*32 + j*8 + i;
        float v = 0.f;
        if (k < GDIM) {
          if (n < HDIM)                 v = W1[k*HDIM + n];
          else if (n >= 160 && n < 310) v = W1[(1000 + k)*HDIM + (n - 160)];
        }
        acc |= ((unsigned)f2fp8(v)) << (8*b);
      }
      dw[d] = acc;
    }
    u32x4 lo = {dw[0], dw[1], dw[2], dw[3]};
    u32x4 hi = {dw[4], dw[5], dw[6], dw[7]};
    *(u32x4*)(w1ab8 + c*10240 + n*32)      = lo;
    *(u32x4*)(w1ab8 + c*10240 + n*32 + 16) = hi;
  } else if (idx < S1 + S2 + S3) {              // w2f8 [c][n][kk], bank swizzle
    int i2 = idx - S1 - S2;
    int c = i2 / 160, n = i2 % 160;
    unsigned dw[8];
    #pragma unroll
    for (int d = 0; d < 8; ++d) {
      unsigned acc = 0;
      #pragma unroll
      for (int b = 0; b < 4; ++b) {
        int kk = d*4 + b;
        int g = kk >> 3, ii = kk & 7;
        int q = g ^ ((n >> 2) & 3);
        int k = c*32 + q*8 + ii;
        float v = (k < HDIM && n < HDIM) ? W2[k*HDIM + n] : 0.f;
        acc |= ((unsigned)f2fp8(v)) << (8*b);
      }
      dw[d] = acc;
    }
    u32x4 lo = {dw[0], dw[1], dw[2], dw[3]};
    u32x4 hi = {dw[4], dw[5], dw[6], dw[7]};
    *(u32x4*)(w2f8 + c*5120 + n*32)      = lo;
    *(u32x4*)(w2f8 + c*5120 + n*32 + 16) = hi;
  } else if (idx < S1 + S2 + S3 + S4) {         // g_i -> fp8 [4096][1024]
    int i = idx - S1 - S2 - S3;
    int row = i >> 8, jd = i & 255;
    int c0 = jd * 4;
    float f0 = (c0     < GDIM) ? g_i[row*GDIM + c0]     : 0.f;
    float f1 = (c0 + 1 < GDIM) ? g_i[row*GDIM + c0 + 1] : 0.f;
    float f2 = (c0 + 2 < GDIM) ? g_i[row*GDIM + c0 + 2] : 0.f;
    float f3 = (c0 + 3 < GDIM) ? g_i[row*GDIM + c0 + 3] : 0.f;
    int d = 0;
    d = __builtin_amdgcn_cvt_pk_fp8_f32(f0, f1, d, false);
    d = __builtin_amdgcn_cvt_pk_fp8_f32(f2, f3, d, true);
    gf8[i] = (unsigned)d;
  } else if (idx < S1 + S2 + S3 + S4 + S5) {    // tabs2: combo phi rows (b1 folded)
    int i = idx - S1 - S2 - S3 - S4;
    int row = i / 160, n = i % 160;
    float acc = 0.f;
    if (n < HDIM) {
      int d = row / 24, g = (row / 3) % 8, sp = row % 3;
      acc = b1[n];
      #pragma unroll
      for (int kk = 0; kk < 20; ++kk) {
        acc += dist_emb [d*20 + kk]  * W1[(3000 + kk)*HDIM + n];
        acc += genre_emb[g*20 + kk]  * W1[(3020 + kk)*HDIM + n];
        acc += spk_emb  [sp*20 + kk] * W1[(3040 + kk)*HDIM + n];
      }
    }
    tabs2[i] = acc;
  } else if (idx < S1 + S2 + S3 + S4 + S5 + S6) {  // itab8: packed combo index
    int p = idx - (S1 + S2 + S3 + S4 + S5);
    itab8[p] = (unsigned char)(did[p]*24 + gid[p]*3 + sid[p]);
  }
}

// ---------- kernel 2: abpre[4096][320](bf16) = g @ [W1a|W1b], fp8 MFMA ----------
__global__ __launch_bounds__(128) void pre_gemm_kernel(
    const unsigned char* __restrict__ gf8, const unsigned char* __restrict__ w1ab8,
    unsigned short* __restrict__ abpre) {
  int wave = threadIdx.x >> 6, lane = threadIdx.x & 63;
  int quad = lane >> 4, n16 = lane & 15;
  int rowbase = blockIdx.x * 32 + wave * 16;
  int colbase = blockIdx.y * 80;

  f32x4 acc[5];
  #pragma unroll
  for (int t = 0; t < 5; ++t) acc[t] = (f32x4){0.f, 0.f, 0.f, 0.f};

  const unsigned char* arow = gf8 + (long)(rowbase + n16) * 1024 + quad*32;

  for (int s = 0; s < 8; ++s) {
    u32x4 Aa = *(const u32x4*)(arow + s*128);
    u32x4 Ab = *(const u32x4*)(arow + s*128 + 16);
    #pragma unroll
    for (int j = 0; j < 4; ++j) {
      long a = (j == 0) ? mk64(Aa[0], Aa[1]) : (j == 1) ? mk64(Aa[2], Aa[3])
             : (j == 2) ? mk64(Ab[0], Ab[1]) : mk64(Ab[2], Ab[3]);
      const unsigned char* bp = w1ab8 + (((s*4 + j)*320 + colbase + n16) * 32 + quad*8);
      #pragma unroll
      for (int t = 0; t < 5; ++t) {
        long b = *(const long*)(bp + t*16*32);
        acc[t] = __builtin_amdgcn_mfma_f32_16x16x32_fp8_fp8(a, b, acc[t], 0, 0, 0);
      }
    }
  }
  #pragma unroll
  for (int t = 0; t < 5; ++t) {
    #pragma unroll
    for (int r = 0; r < 4; ++r) {
      int row = rowbase + quad*4 + r;
      abpre[(long)row * 320 + colbase + t*16 + n16] = (unsigned short)f2bf(acc[t][r]);
    }
  }
}

// ---------- kernel 3: double-buffered staged MLP (r12 structure) with the
// extras term fused into the epilogue (abpre/tabs2 are L2-hot; no HBM stream) --
__global__ __launch_bounds__(256) void mlp_kernel(
    const unsigned char* __restrict__ gf8,
    const unsigned short* __restrict__ abpre,
    const float* __restrict__ tabs2,
    const unsigned char* __restrict__ itab8,
    const unsigned char* __restrict__ w1c8,
    const unsigned char* __restrict__ w2f8,
    const float* __restrict__ ms,
    const float* __restrict__ W3, const float* __restrict__ b2,
    const float* __restrict__ b3,
    const int* __restrict__ mention_ids, const int* __restrict__ antecedent_ids,
    const int* __restrict__ seg_ids, const int* __restrict__ offs,
    float* __restrict__ sgrid) {

  __shared__ __align__(16) unsigned char lds[53248];

  int tid = threadIdx.x;
  int wave = tid >> 6, lane = tid & 63;
  int quad = lane >> 4, n16 = lane & 15;
  int lp0 = blockIdx.x * 128;
  int gp0 = lp0;
  int wrow = wave * 32;

  int jj = (lane & 3) ^ ((lane >> 2) & 3) ^ ((lane >> 4) & 1);
  int srow = lane >> 2;
  int swA = quad ^ (n16 & 3) ^ ((n16 >> 2) & 1);
  int swB = quad ^ ((n16 >> 2) & 3);

  const unsigned char* pA0 =
      gf8 + (long)mention_ids[gp0 + wave*16 + srow] * 1024 + jj*16;
  const unsigned char* pA1 =
      gf8 + (long)mention_ids[gp0 + (wave + 4)*16 + srow] * 1024 + jj*16;
  const unsigned char* pA2 =
      gf8 + (long)antecedent_ids[gp0 + wave*16 + srow] * 1024 + jj*16;
  const unsigned char* pA3 =
      gf8 + (long)antecedent_ids[gp0 + (wave + 4)*16 + srow] * 1024 + jj*16;
  int dA0 = wave*1024,      dA1 = (wave + 4)*1024;
  int dA2 = 8192 + dA0,     dA3 = 8192 + dA1;

  f32x4 acc0[10], acc1[10];
  #pragma unroll
  for (int t = 0; t < 10; ++t) {
    acc0[t] = (f32x4){0.f, 0.f, 0.f, 0.f};
    acc1[t] = (f32x4){0.f, 0.f, 0.f, 0.f};
  }

  auto issue = [&](int s, int buf) {
    unsigned char* base = lds + buf*26624;
    long so = (long)s * 64;
    __builtin_amdgcn_global_load_lds((const unsigned int*)(pA0 + so),
        (unsigned int*)(base + dA0 + lane*16), 16, 0, 0);
    __builtin_amdgcn_global_load_lds((const unsigned int*)(pA1 + so),
        (unsigned int*)(base + dA1 + lane*16), 16, 0, 0);
    __builtin_amdgcn_global_load_lds((const unsigned int*)(pA2 + so),
        (unsigned int*)(base + dA2 + lane*16), 16, 0, 0);
    __builtin_amdgcn_global_load_lds((const unsigned int*)(pA3 + so),
        (unsigned int*)(base + dA3 + lane*16), 16, 0, 0);
    const unsigned char* wsrc = w1c8 + (long)s*10240;
    __builtin_amdgcn_global_load_lds((const unsigned int*)(wsrc + wave*1024 + (long)lane*16),
        (unsigned int*)(base + 16384 + wave*1024 + lane*16), 16, 0, 0);
    __builtin_amdgcn_global_load_lds((const unsigned int*)(wsrc + (wave+4)*1024 + (long)lane*16),
        (unsigned int*)(base + 16384 + (wave+4)*1024 + lane*16), 16, 0, 0);
    if (wave < 2)
      __builtin_amdgcn_global_load_lds((const unsigned int*)(wsrc + (wave+8)*1024 + (long)lane*16),
          (unsigned int*)(base + 16384 + (wave+8)*1024 + lane*16), 16, 0, 0);
  };

  issue(0, 0);
  for (int s = 0; s < 16; ++s) {
    __syncthreads();
    if (s < 15) issue(s + 1, (s + 1) & 1);
    const unsigned char* cb = lds + (s & 1)*26624;

    u32x4 M0 = *(const u32x4*)(cb + (wrow + n16)*64 + swA*16);
    u32x4 C0 = *(const u32x4*)(cb + 8192 + (wrow + n16)*64 + swA*16);
    u32x4 M1 = *(const u32x4*)(cb + (wrow + 16 + n16)*64 + swA*16);
    u32x4 C1 = *(const u32x4*)(cb + 8192 + (wrow + 16 + n16)*64 + swA*16);
    u32x4 P0 = fp8prod16(M0, C0);
    u32x4 P1 = fp8prod16(M1, C1);

    #pragma unroll
    for (int j = 0; j < 2; ++j) {
      long a0 = (j == 0) ? mk64(P0[0], P0[1]) : mk64(P0[2], P0[3]);
      long a1 = (j == 0) ? mk64(P1[0], P1[1]) : mk64(P1[2], P1[3]);
      const unsigned char* bp = cb + 16384 + j*5120 + n16*32 + swB*8;
      #pragma unroll
      for (int t = 0; t < 10; ++t) {
        long b = *(const long*)(bp + t*512);
        acc0[t] = __builtin_amdgcn_mfma_f32_16x16x32_fp8_fp8(a0, b, acc0[t], 0, 0, 0);
        acc1[t] = __builtin_amdgcn_mfma_f32_16x16x32_fp8_fp8(a1, b, acc1[t], 0, 0, 0);
      }
    }
  }
  __syncthreads();

  for (int r = wave; r < 25; r += 4) {
    __builtin_amdgcn_global_load_lds(
        (const unsigned int*)(w2f8 + r*1024 + (long)lane*16),
        (unsigned int*)(lds + 26624 + r*1024), 16, 0, 0);
  }

  // epilogue: extras computed on the fly from abpre (L2-hot) + tabs2 + itab8
  unsigned char* h1w = lds + wave * 5888;   // [32][184] fp8
  #pragma unroll
  for (int r = 0; r < 4; ++r) {
    int row0 = quad*4 + r;
    int gpA = gp0 + wrow + row0;        // rows for acc0
    int gpB = gpA + 16;                 // rows for acc1
    const unsigned short* pmA = abpre + (long)mention_ids[gpA]*320;
    const unsigned short* paA = abpre + (long)antecedent_ids[gpA]*320 + 160;
    const float*          tbA = tabs2 + (long)itab8[gpA]*160;
    const unsigned short* pmB = abpre + (long)mention_ids[gpB]*320;
    const unsigned short* paB = abpre + (long)antecedent_ids[gpB]*320 + 160;
    const float*          tbB = tabs2 + (long)itab8[gpB]*160;
    #pragma unroll
    for (int t = 0; t < 10; ++t) {
      int n = t*16 + n16;
      float v0 = acc0[t][r] + bf2f(pmA[n]) + bf2f(paA[n]) + tbA[n];
      float v1 = acc1[t][r] + bf2f(pmB[n]) + bf2f(paB[n]) + tbB[n];
      h1w[row0*184 + n]        = f2fp8(fmaxf(v0, 0.f));
      h1w[(16 + row0)*184 + n] = f2fp8(fmaxf(v1, 0.f));
    }
  }
  __syncthreads();

  float bias3 = b3[0];
  float w3v[10], b2v[10];
  #pragma unroll
  for (int t = 0; t < 10; ++t) {
    int n = t*16 + n16;
    w3v[t] = (n < HDIM) ? W3[n] : 0.f;
    b2v[t] = (n < HDIM) ? b2[n] : 0.f;
  }

  #pragma unroll
  for (int tile = 0; tile < 2; ++tile) {
    f32x4 acc2[10];
    #pragma unroll
    for (int t = 0; t < 10; ++t) acc2[t] = (f32x4){0.f, 0.f, 0.f, 0.f};

    #pragma unroll
    for (int c = 0; c < 5; ++c) {
      long a = *(const long*)(h1w + (tile*16 + n16)*184 + c*32 + quad*8);
      const unsigned char* bp = lds + 26624 + (c*160 + n16)*32 + swB*8;
      #pragma unroll
      for (int t = 0; t < 10; ++t) {
        long b = *(const long*)(bp + t*512);
        acc2[t] = __builtin_amdgcn_mfma_f32_16x16x32_fp8_fp8(a, b, acc2[t], 0, 0, 0);
      }
    }

    float part[4] = {0.f, 0.f, 0.f, 0.f};
    #pragma unroll
    for (int t = 0; t < 10; ++t) {
      #pragma unroll
      for (int r = 0; r < 4; ++r) {
        float h2 = fmaxf(acc2[t][r] + b2v[t], 0.f);
        part[r] += h2 * w3v[t];
      }
    }
    for (int msk = 1; msk < 16; msk <<= 1) {
      #pragma unroll
      for (int r = 0; r < 4; ++r) part[r] += __shfl_xor(part[r], msk);
    }

    if (n16 == 0) {
      #pragma unroll
      for (int r = 0; r < 4; ++r) {
        int gp = gp0 + wrow + tile*16 + quad*4 + r;
        float sc = part[r] + bias3 + ms[mention_ids[gp]] + ms[antecedent_ids[gp]];
        sgrid[seg_ids[gp] * KMAX + offs[gp]] = sc;
      }
    }
  }
}

// ---------- kernel 4: per-group softmax (+epsilon) and full output fill ----------
__global__ __launch_bounds__(128) void softmax_kernel(const float* __restrict__ sgrid,
                                                      const int* __restrict__ lengths,
                                                      float* __restrict__ out) {
  int b = blockIdx.x, t = threadIdx.x;
  if (b == 0) {
    out[t] = (t == 0) ? 1.0f : 1000.0f;
    if (t == 0) out[128] = 1000.0f;
    return;
  }
  int m = b - 1;
  int len = lengths[m];
  float s = (t < len) ? sgrid[m * KMAX + t] : -1e30f;

  __shared__ float redA[2];
  __shared__ float redB[2];

  float v = s;
  #pragma unroll
  for (int o = 32; o >= 1; o >>= 1) v = fmaxf(v, __shfl_xor(v, o));
  if ((t & 63) == 0) redA[t >> 6] = v;
  __syncthreads();
  float mx = fmaxf(fmaxf(redA[0], redA[1]), 0.0f);

  float e = (t < len) ? expf(s - mx) : 0.f;
  float sum = e;
  #pragma unroll
  for (int o = 32; o >= 1; o >>= 1) sum += __shfl_xor(sum, o);
  if ((t & 63) == 0) redB[t >> 6] = sum;
  __syncthreads();

  float eps_e = expf(-mx);
  float denom = redB[0] + redB[1] + eps_e;

  float* row = out + (long)(m + 1) * 129;
  float val;
  if (t < len)       val = e / denom;
  else if (t == len) val = eps_e / denom;
  else               val = 1000.0f;
  row[t] = val;
  if (t == 0) row[128] = (len == KMAX) ? (eps_e / denom) : 1000.0f;
}

extern "C" void kernel_launch(void* const* d_in, const int* in_sizes, int n_in,
                              void* d_out, int out_size, void* d_ws, size_t ws_size,
                              hipStream_t stream) {
  const float* g_i        = (const float*)d_in[0];
  const float* ms         = (const float*)d_in[1];
  const float* dist_emb   = (const float*)d_in[2];
  const float* genre_emb  = (const float*)d_in[3];
  const float* spk_emb    = (const float*)d_in[4];
  const float* W1         = (const float*)d_in[5];
  const float* b1         = (const float*)d_in[6];
  const float* W2         = (const float*)d_in[7];
  const float* b2         = (const float*)d_in[8];
  const float* W3         = (const float*)d_in[9];
  const float* b3         = (const float*)d_in[10];
  const int* mention_ids    = (const int*)d_in[11];
  const int* antecedent_ids = (const int*)d_in[12];
  const int* dist_ids       = (const int*)d_in[13];
  const int* genre_ids      = (const int*)d_in[14];
  const int* spk_ids        = (const int*)d_in[15];
  const int* lengths        = (const int*)d_in[16];
  const int* seg_ids        = (const int*)d_in[17];
  const int* offsets        = (const int*)d_in[18];

  char* ws = (char*)d_ws;
  unsigned char* w1c8  = (unsigned char*)(ws + OFF_W1C8);
  unsigned char* w1ab8 = (unsigned char*)(ws + OFF_W1AB8);
  unsigned char* w2f8  = (unsigned char*)(ws + OFF_W2F8);
  unsigned short* abpre = (unsigned short*)(ws + OFF_ABPRE);
  float* tabs2  = (float*)(ws + OFF_TABS2);
  float* sgrid  = (float*)(ws + OFF_SGRID);
  unsigned char* gf8  = (unsigned char*)(ws + OFF_GF8);
  unsigned char* itab8 = (unsigned char*)(ws + OFF_ITAB);

  const int prepN = S1 + S2 + S3 + S4 + S5 + S6;
  prep_kernel<<<(prepN + 255)/256, 256, 0, stream>>>(W1, W2, g_i,
                                                     dist_emb, genre_emb, spk_emb, b1,
                                                     dist_ids, genre_ids, spk_ids,
                                                     w1c8, w1ab8, w2f8,
                                                     (unsigned*)gf8, tabs2, itab8);
  dim3 gpre(NPOOL/32, 4);
  pre_gemm_kernel<<<gpre, 128, 0, stream>>>(gf8, w1ab8, abpre);
  mlp_kernel<<<P_TOTAL/128, 256, 0, stream>>>(gf8, abpre, tabs2, itab8,
                                              w1c8, w2f8, ms,
                                              W3, b2, b3,
                                              mention_ids, antecedent_ids,
                                              seg_ids, offsets, sgrid);
  softmax_kernel<<<MGRP + 1, 128, 0, stream>>>(sgrid, lengths, (float*)d_out);
}